// Round 8
// baseline (319.102 us; speedup 1.0000x reference)
//
#include <hip/hip_runtime.h>

#define N_NODES 50000
#define N_EDGES 400000
#define N_TILES 782          // ceil(50000/64)
#define GRID_G  512
#define HIST_BLOCKS 1563     // ceil(400000/256)

#define N_PAD   50176        // 196 * 256

// k_prep_w segment offsets (thread ids)
#define PZ_CNT   50176                    // [0, PZ_CNT): zero counts
#define PO_TB    (PZ_CNT)                 // 8192: Tb (bf16)
#define PO_W1EB  (PO_TB + 8192)           // 65536: W1ebT
#define PO_W2E   (PO_W1EB + 65536)        // 65536: W2eT
#define PO_W1S   (PO_W2E + 65536)         // 32768: W1sT
#define PO_W2S   (PO_W1S + 32768)         // 32768: W2sT
#define P_TOTAL  (PO_W2S + 32768)         // 254976 = 996 * 256

typedef __attribute__((ext_vector_type(8))) short short8;
typedef __attribute__((ext_vector_type(4))) float floatx4;

__device__ __forceinline__ float bf2f(unsigned short u) {
    union { unsigned int i; float f; } v; v.i = ((unsigned int)u) << 16; return v.f;
}
__device__ __forceinline__ unsigned short f2bf(float f) {
    union { float f; unsigned int i; } v; v.f = f;
    unsigned int b = v.i;
    return (unsigned short)((b + 0x7FFFu + ((b >> 16) & 1u)) >> 16);
}

// stage one 64-row x 128-col f32 tile -> swizzled bf16 LDS tile (16 KB)
__device__ __forceinline__ void stage_feat(const float* __restrict__ features,
                                           unsigned short* __restrict__ fbs,
                                           int mbase, int t) {
    int row = t >> 2, seg = t & 3;
    int node = mbase + row; if (node >= N_NODES) node = N_NODES - 1;
    const float* p = &features[(size_t)node * 128 + seg * 32];
    #pragma unroll
    for (int i = 0; i < 4; ++i) {
        float4 x = *(const float4*)&p[i * 8];
        float4 y = *(const float4*)&p[i * 8 + 4];
        short8 hv;
        hv[0] = (short)f2bf(x.x); hv[1] = (short)f2bf(x.y);
        hv[2] = (short)f2bf(x.z); hv[3] = (short)f2bf(x.w);
        hv[4] = (short)f2bf(y.x); hv[5] = (short)f2bf(y.y);
        hv[6] = (short)f2bf(y.z); hv[7] = (short)f2bf(y.w);
        int c = seg * 4 + i;
        int cp = c ^ (row & 7);
        *(short8*)&fbs[row * 128 + cp * 8] = hv;
    }
}

// ---------------- weight prep + counts zero (fused) ----------------
__device__ __forceinline__ void tr_seg(const float* __restrict__ src, unsigned short* __restrict__ dst,
                                       int K, int Ncols, int idx) {
    int c = idx / K, k = idx - c * K;
    dst[idx] = f2bf(src[k * Ncols + c]);
}

__global__ void k_prep_w(const float* __restrict__ e_emb, const float* __restrict__ W1e,
                         const float* __restrict__ b1e, const float* __restrict__ W2e,
                         const float* __restrict__ W1s, const float* __restrict__ W2s,
                         unsigned short* __restrict__ Tb, unsigned short* __restrict__ W1ebT,
                         unsigned short* __restrict__ W2eT, unsigned short* __restrict__ W1sT,
                         unsigned short* __restrict__ W2sT, int* __restrict__ counts) {
    int tid = blockIdx.x * 256 + threadIdx.x;
    if (tid < PZ_CNT) {
        counts[tid] = 0;
    } else if (tid < PO_W1EB) {
        int idx = tid - PO_TB;
        int typ = idx >> 9, col = idx & 511;
        float acc = b1e[col];
        for (int k = 0; k < 128; ++k)
            acc += e_emb[typ * 128 + k] * W1e[k * 512 + col];
        Tb[idx] = f2bf(acc);                // bf16: one 16B load per edge in gather
    } else if (tid < PO_W2E) {
        tr_seg(W1e + 128 * 512, W1ebT, 128, 512, tid - PO_W1EB);
    } else if (tid < PO_W1S) {
        tr_seg(W2e, W2eT, 512, 128, tid - PO_W2E);
    } else if (tid < PO_W2S) {
        tr_seg(W1s, W1sT, 128, 256, tid - PO_W1S);
    } else if (tid < P_TOTAL) {
        tr_seg(W2s, W2sT, 256, 128, tid - PO_W2S);
    }
}

// ---------------- single-block full scan: row_start/cursor = exclusive scan(counts) ----------------
__global__ __launch_bounds__(1024) void k_scan(const int* __restrict__ counts,
                                               int* __restrict__ row_start,
                                               int* __restrict__ cursor) {
    __shared__ int ws[16];
    __shared__ int carry_s;
    int t = threadIdx.x, lane = t & 63, wv = t >> 6;
    int carry = 0;
    for (int base = 0; base < N_PAD; base += 1024) {
        int v = counts[base + t];
        int x = v;
        #pragma unroll
        for (int d = 1; d < 64; d <<= 1) {
            int y = __shfl_up(x, d, 64);
            if (lane >= d) x += y;
        }
        if (lane == 63) ws[wv] = x;
        __syncthreads();
        int woff = 0;
        for (int w = 0; w < wv; ++w) woff += ws[w];
        int excl = x - v + woff + carry;
        row_start[base + t] = excl;
        cursor[base + t] = excl;
        __syncthreads();
        if (t == 0) {
            int tot = 0;
            #pragma unroll
            for (int w = 0; w < 16; ++w) tot += ws[w];
            carry_s = tot;
        }
        __syncthreads();
        carry += carry_s;
    }
}

// pack src|type<<16 (src < 65536)
__global__ void k_scatter(const int* __restrict__ edge_src, const int* __restrict__ edge_dst,
                          const int* __restrict__ edge_type, int* __restrict__ cursor,
                          int* __restrict__ sorted_pack) {
    int e = blockIdx.x * 256 + threadIdx.x;
    if (e < N_EDGES) {
        int d = edge_dst[e];
        int pos = atomicAdd(&cursor[d], 1);
        sorted_pack[pos] = edge_src[e] | (edge_type[e] << 16);
    }
}

// ---------------- merged kernel: G GEMM role / self MLP role / histogram role ----------------

__device__ __forceinline__ void gemm_G_role(const float* __restrict__ features,
                                            const unsigned short* __restrict__ W1ebT,
                                            unsigned short* __restrict__ G,
                                            unsigned short* fbs, int bid) {
    int t = threadIdx.x, lane = t & 63, wave = t >> 6;
    int r = lane & 15, quad = lane >> 4;

    short8 bfrag[8][4];
    #pragma unroll
    for (int ct = 0; ct < 8; ++ct)
        #pragma unroll
        for (int ks = 0; ks < 4; ++ks)
            bfrag[ct][ks] = *(const short8*)&W1ebT[(wave * 128 + ct * 16 + r) * 128 + ks * 32 + quad * 8];

    for (int tile = bid; tile < N_TILES; tile += GRID_G) {
        int mbase = tile * 64;
        stage_feat(features, fbs, mbase, t);
        __syncthreads();
        #pragma unroll
        for (int m = 0; m < 4; ++m) {
            floatx4 acc[8];
            #pragma unroll
            for (int i = 0; i < 8; ++i) acc[i] = (floatx4){0.f, 0.f, 0.f, 0.f};
            #pragma unroll
            for (int ks = 0; ks < 4; ++ks) {
                int row = m * 16 + r;
                int cp = (ks * 4 + quad) ^ (row & 7);
                short8 a = *(const short8*)&fbs[row * 128 + cp * 8];
                #pragma unroll
                for (int ct = 0; ct < 8; ++ct)
                    acc[ct] = __builtin_amdgcn_mfma_f32_16x16x32_bf16(a, bfrag[ct][ks], acc[ct], 0, 0, 0);
            }
            #pragma unroll
            for (int ct = 0; ct < 8; ++ct)
                #pragma unroll
                for (int p = 0; p < 4; ++p) {
                    int node = mbase + m * 16 + quad * 4 + p;
                    if (node < N_NODES)
                        G[(size_t)node * 512 + wave * 128 + ct * 16 + r] = f2bf(acc[ct][p]);
                }
        }
        __syncthreads();
    }
}

__device__ __forceinline__ void self_role(const float* __restrict__ features,
                                          const unsigned short* __restrict__ W1sT,
                                          const float* __restrict__ b1s,
                                          const unsigned short* __restrict__ W2sT,
                                          const float* __restrict__ b2s,
                                          float* __restrict__ out,
                                          unsigned short* fbs, unsigned short* hss, int bid) {
    int t = threadIdx.x, lane = t & 63, wave = t >> 6;
    int r = lane & 15, quad = lane >> 4;

    short8 b1f[4][4];
    #pragma unroll
    for (int ct = 0; ct < 4; ++ct)
        #pragma unroll
        for (int ks = 0; ks < 4; ++ks)
            b1f[ct][ks] = *(const short8*)&W1sT[(wave * 64 + ct * 16 + r) * 128 + ks * 32 + quad * 8];
    short8 b2f[2][8];
    #pragma unroll
    for (int ct = 0; ct < 2; ++ct)
        #pragma unroll
        for (int ks = 0; ks < 8; ++ks)
            b2f[ct][ks] = *(const short8*)&W2sT[(wave * 32 + ct * 16 + r) * 256 + ks * 32 + quad * 8];
    float bias1[4], bias2[2];
    #pragma unroll
    for (int ct = 0; ct < 4; ++ct) bias1[ct] = b1s[wave * 64 + ct * 16 + r];
    #pragma unroll
    for (int ct = 0; ct < 2; ++ct) bias2[ct] = b2s[wave * 32 + ct * 16 + r];

    for (int tile = bid; tile < N_TILES; tile += GRID_G) {
        int mbase = tile * 64;
        stage_feat(features, fbs, mbase, t);
        __syncthreads();

        #pragma unroll
        for (int m = 0; m < 4; ++m) {
            floatx4 acc[4];
            #pragma unroll
            for (int i = 0; i < 4; ++i) acc[i] = (floatx4){0.f, 0.f, 0.f, 0.f};
            #pragma unroll
            for (int ks = 0; ks < 4; ++ks) {
                int row = m * 16 + r;
                int cp = (ks * 4 + quad) ^ (row & 7);
                short8 a = *(const short8*)&fbs[row * 128 + cp * 8];
                #pragma unroll
                for (int ct = 0; ct < 4; ++ct)
                    acc[ct] = __builtin_amdgcn_mfma_f32_16x16x32_bf16(a, b1f[ct][ks], acc[ct], 0, 0, 0);
            }
            #pragma unroll
            for (int ct = 0; ct < 4; ++ct)
                #pragma unroll
                for (int p = 0; p < 4; ++p) {
                    int lrow = m * 16 + quad * 4 + p;
                    int col = wave * 64 + ct * 16 + r;
                    float v = fmaxf(acc[ct][p] + bias1[ct], 0.f);
                    int cp = (col >> 3) ^ (lrow & 7);
                    hss[lrow * 256 + cp * 8 + (col & 7)] = f2bf(v);
                }
        }
        __syncthreads();

        #pragma unroll
        for (int m = 0; m < 4; ++m) {
            floatx4 acc[2];
            #pragma unroll
            for (int i = 0; i < 2; ++i) acc[i] = (floatx4){0.f, 0.f, 0.f, 0.f};
            #pragma unroll
            for (int ks = 0; ks < 8; ++ks) {
                int row = m * 16 + r;
                int cp = (ks * 4 + quad) ^ (row & 7);
                short8 a = *(const short8*)&hss[row * 256 + cp * 8];
                #pragma unroll
                for (int ct = 0; ct < 2; ++ct)
                    acc[ct] = __builtin_amdgcn_mfma_f32_16x16x32_bf16(a, b2f[ct][ks], acc[ct], 0, 0, 0);
            }
            #pragma unroll
            for (int ct = 0; ct < 2; ++ct)
                #pragma unroll
                for (int p = 0; p < 4; ++p) {
                    int node = mbase + m * 16 + quad * 4 + p;
                    if (node < N_NODES)
                        out[(size_t)node * 256 + wave * 32 + ct * 16 + r] = acc[ct][p] + bias2[ct];
                }
        }
        __syncthreads();
    }
}

__global__ __launch_bounds__(256, 2) void k_node(const float* __restrict__ features,
                                                 const unsigned short* __restrict__ W1ebT,
                                                 unsigned short* __restrict__ G,
                                                 const unsigned short* __restrict__ W1sT,
                                                 const float* __restrict__ b1s,
                                                 const unsigned short* __restrict__ W2sT,
                                                 const float* __restrict__ b2s,
                                                 float* __restrict__ out,
                                                 const int* __restrict__ edge_dst,
                                                 int* __restrict__ counts) {
    __shared__ unsigned short fbs[64 * 128];   // 16 KB
    __shared__ unsigned short hss[64 * 256];   // 32 KB (self role only)
    int bid = blockIdx.x;
    if (bid < GRID_G) {
        gemm_G_role(features, W1ebT, G, fbs, bid);
    } else if (bid < 2 * GRID_G) {
        self_role(features, W1sT, b1s, W2sT, b2s, out, fbs, hss, bid - GRID_G);
    } else {
        int e = (bid - 2 * GRID_G) * 256 + threadIdx.x;
        if (e < N_EDGES) atomicAdd(&counts[edge_dst[e]], 1);
    }
}

// ---------------- aggregation: H[n] = sum_e relu(G[src]+T[type])   [N,512] bf16 ----------------
// R4-proven shape: wave-per-node, 12500 short blocks, no LDS, 4-edge unroll, bf16 Tb.
__global__ __launch_bounds__(256) void k_agg(const unsigned short* __restrict__ G,
                                             const unsigned short* __restrict__ Tb,
                                             const int* __restrict__ row_start,
                                             const int* __restrict__ sorted_pack,
                                             unsigned short* __restrict__ H) {
    int t = threadIdx.x, lane = t & 63, wave = t >> 6;
    int node = blockIdx.x * 4 + wave;
    if (node >= N_NODES) return;
    int beg = row_start[node], end = row_start[node + 1];
    float acc[8] = {0.f, 0.f, 0.f, 0.f, 0.f, 0.f, 0.f, 0.f};
    int off = lane * 8;
    int e = beg;
    for (; e + 4 <= end; e += 4) {
        int v0 = sorted_pack[e],     v1 = sorted_pack[e + 1];
        int v2 = sorted_pack[e + 2], v3 = sorted_pack[e + 3];
        short8 g0 = *(const short8*)&G[(unsigned)(v0 & 0xFFFF) * 512 + off];
        short8 g1 = *(const short8*)&G[(unsigned)(v1 & 0xFFFF) * 512 + off];
        short8 g2 = *(const short8*)&G[(unsigned)(v2 & 0xFFFF) * 512 + off];
        short8 g3 = *(const short8*)&G[(unsigned)(v3 & 0xFFFF) * 512 + off];
        short8 u0 = *(const short8*)&Tb[(v0 >> 16) * 512 + off];
        short8 u1 = *(const short8*)&Tb[(v1 >> 16) * 512 + off];
        short8 u2 = *(const short8*)&Tb[(v2 >> 16) * 512 + off];
        short8 u3 = *(const short8*)&Tb[(v3 >> 16) * 512 + off];
        #pragma unroll
        for (int k = 0; k < 8; ++k) {
            acc[k] += fmaxf(bf2f((unsigned short)g0[k]) + bf2f((unsigned short)u0[k]), 0.f);
            acc[k] += fmaxf(bf2f((unsigned short)g1[k]) + bf2f((unsigned short)u1[k]), 0.f);
            acc[k] += fmaxf(bf2f((unsigned short)g2[k]) + bf2f((unsigned short)u2[k]), 0.f);
            acc[k] += fmaxf(bf2f((unsigned short)g3[k]) + bf2f((unsigned short)u3[k]), 0.f);
        }
    }
    for (; e < end; ++e) {
        int v = sorted_pack[e];
        short8 g0 = *(const short8*)&G[(unsigned)(v & 0xFFFF) * 512 + off];
        short8 u0 = *(const short8*)&Tb[(v >> 16) * 512 + off];
        #pragma unroll
        for (int k = 0; k < 8; ++k)
            acc[k] += fmaxf(bf2f((unsigned short)g0[k]) + bf2f((unsigned short)u0[k]), 0.f);
    }
    short8 hv;
    #pragma unroll
    for (int k = 0; k < 8; ++k) hv[k] = (short)f2bf(acc[k]);
    *(short8*)&H[(size_t)node * 512 + off] = hv;
}

// ---------------- out[:,128:] = H @ W2e + deg*b2e ----------------
__global__ __launch_bounds__(256, 2) void k_gemm_H(const unsigned short* __restrict__ H,
                                                   const int* __restrict__ row_start,
                                                   const unsigned short* __restrict__ W2eT,
                                                   const float* __restrict__ b2e,
                                                   float* __restrict__ out) {
    __shared__ unsigned short hls[64 * 512];   // 64 KB
    int t = threadIdx.x, lane = t & 63, wave = t >> 6;
    int r = lane & 15, quad = lane >> 4;

    short8 bf[2][16];
    #pragma unroll
    for (int ct = 0; ct < 2; ++ct)
        #pragma unroll
        for (int ks = 0; ks < 16; ++ks)
            bf[ct][ks] = *(const short8*)&W2eT[(wave * 32 + ct * 16 + r) * 512 + ks * 32 + quad * 8];
    float bias[2];
    #pragma unroll
    for (int ct = 0; ct < 2; ++ct) bias[ct] = b2e[wave * 32 + ct * 16 + r];

    for (int tile = blockIdx.x; tile < N_TILES; tile += GRID_G) {
        int nbase = tile * 64;
        {
            int row = t >> 2, seg = t & 3;
            int node = nbase + row; if (node >= N_NODES) node = N_NODES - 1;
            const unsigned short* p = &H[(size_t)node * 512 + seg * 128];
            #pragma unroll
            for (int i = 0; i < 16; ++i) {
                int c = seg * 16 + i;
                int cp = c ^ (row & 7);
                *(short8*)&hls[row * 512 + cp * 8] = *(const short8*)&p[i * 8];
            }
        }
        __syncthreads();
        #pragma unroll
        for (int m = 0; m < 4; ++m) {
            floatx4 acc[2];
            #pragma unroll
            for (int i = 0; i < 2; ++i) acc[i] = (floatx4){0.f, 0.f, 0.f, 0.f};
            #pragma unroll
            for (int ks = 0; ks < 16; ++ks) {
                int row = m * 16 + r;
                int cp = (ks * 4 + quad) ^ (row & 7);
                short8 a = *(const short8*)&hls[row * 512 + cp * 8];
                #pragma unroll
                for (int ct = 0; ct < 2; ++ct)
                    acc[ct] = __builtin_amdgcn_mfma_f32_16x16x32_bf16(a, bf[ct][ks], acc[ct], 0, 0, 0);
            }
            #pragma unroll
            for (int p = 0; p < 4; ++p) {
                int node = nbase + m * 16 + quad * 4 + p;
                if (node < N_NODES) {
                    float dg = (float)(row_start[node + 1] - row_start[node]);
                    #pragma unroll
                    for (int ct = 0; ct < 2; ++ct)
                        out[(size_t)node * 256 + 128 + wave * 32 + ct * 16 + r] = acc[ct][p] + dg * bias[ct];
                }
            }
        }
        __syncthreads();
    }
}

// ---------------- launch ----------------

extern "C" void kernel_launch(void* const* d_in, const int* in_sizes, int n_in,
                              void* d_out, int out_size, void* d_ws, size_t ws_size,
                              hipStream_t stream) {
    const float* features  = (const float*)d_in[0];
    const int*   edge_src  = (const int*)d_in[1];
    const int*   edge_dst  = (const int*)d_in[2];
    const int*   edge_type = (const int*)d_in[3];
    const float* e_emb     = (const float*)d_in[4];
    const float* W1e       = (const float*)d_in[5];
    const float* b1e       = (const float*)d_in[6];
    const float* W2e       = (const float*)d_in[7];
    const float* b2e       = (const float*)d_in[8];
    const float* W1s       = (const float*)d_in[9];
    const float* b1s       = (const float*)d_in[10];
    const float* W2s       = (const float*)d_in[11];
    const float* b2s       = (const float*)d_in[12];
    float* out = (float*)d_out;

    char* ws = (char*)d_ws;
    size_t off = 0;
    auto alloc = [&](size_t bytes) {
        char* p = ws + off;
        off += (bytes + 255) & ~(size_t)255;
        return p;
    };
    unsigned short* G        = (unsigned short*)alloc((size_t)N_NODES * 512 * 2);
    unsigned short* H        = (unsigned short*)alloc((size_t)N_NODES * 512 * 2);
    unsigned short* Tb       = (unsigned short*)alloc(16 * 512 * 2);
    unsigned short* W1ebT    = (unsigned short*)alloc(512 * 128 * 2);
    unsigned short* W2eT     = (unsigned short*)alloc(128 * 512 * 2);
    unsigned short* W1sT     = (unsigned short*)alloc(256 * 128 * 2);
    unsigned short* W2sT     = (unsigned short*)alloc(128 * 256 * 2);
    int* counts      = (int*)alloc((size_t)N_PAD * 4);
    int* row_start   = (int*)alloc((size_t)N_PAD * 4);
    int* cursor      = (int*)alloc((size_t)N_PAD * 4);
    int* sorted_pack = (int*)alloc((size_t)N_EDGES * 4);

    k_prep_w<<<P_TOTAL / 256, 256, 0, stream>>>(e_emb, W1e, b1e, W2e, W1s, W2s,
                                                Tb, W1ebT, W2eT, W1sT, W2sT, counts);

    k_node<<<GRID_G * 2 + HIST_BLOCKS, 256, 0, stream>>>(features, W1ebT, G, W1sT, b1s,
                                                         W2sT, b2s, out, edge_dst, counts);

    k_scan<<<1, 1024, 0, stream>>>(counts, row_start, cursor);
    k_scatter<<<HIST_BLOCKS, 256, 0, stream>>>(edge_src, edge_dst, edge_type,
                                               cursor, sorted_pack);

    k_agg<<<(N_NODES + 3) / 4, 256, 0, stream>>>(G, Tb, row_start, sorted_pack, H);
    k_gemm_H<<<GRID_G, 256, 0, stream>>>(H, row_start, W2eT, b2e, out);
}

// Round 9
// 278.836 us; speedup vs baseline: 1.1444x; 1.1444x over previous
//
#include <hip/hip_runtime.h>

#define N_NODES 50000
#define N_EDGES 400000
#define N_TILES 782          // ceil(50000/64)
#define GRID_G  512

#define N_PAD   50176        // 196 * 256
#define NBLK    196

// k_prep_w segment offsets (thread ids)
#define PZ_CNT   50176                    // [0, PZ_CNT): zero counts
#define PO_TB    (PZ_CNT)                 // 8192: Tb (bf16)
#define PO_W1EB  (PO_TB + 8192)           // 65536: W1ebT
#define PO_W2E   (PO_W1EB + 65536)        // 65536: W2eT
#define PO_W1S   (PO_W2E + 65536)         // 32768: W1sT
#define PO_W2S   (PO_W1S + 32768)         // 32768: W2sT
#define P_TOTAL  (PO_W2S + 32768)         // 254976 = 996 * 256

typedef __attribute__((ext_vector_type(8))) short short8;
typedef __attribute__((ext_vector_type(4))) float floatx4;

__device__ __forceinline__ float bf2f(unsigned short u) {
    union { unsigned int i; float f; } v; v.i = ((unsigned int)u) << 16; return v.f;
}
__device__ __forceinline__ unsigned short f2bf(float f) {
    union { float f; unsigned int i; } v; v.f = f;
    unsigned int b = v.i;
    return (unsigned short)((b + 0x7FFFu + ((b >> 16) & 1u)) >> 16);
}

// stage one 64-row x 128-col f32 tile -> swizzled bf16 LDS tile (16 KB)
__device__ __forceinline__ void stage_feat(const float* __restrict__ features,
                                           unsigned short* __restrict__ fbs,
                                           int mbase, int t) {
    int row = t >> 2, seg = t & 3;
    int node = mbase + row; if (node >= N_NODES) node = N_NODES - 1;
    const float* p = &features[(size_t)node * 128 + seg * 32];
    #pragma unroll
    for (int i = 0; i < 4; ++i) {
        float4 x = *(const float4*)&p[i * 8];
        float4 y = *(const float4*)&p[i * 8 + 4];
        short8 hv;
        hv[0] = (short)f2bf(x.x); hv[1] = (short)f2bf(x.y);
        hv[2] = (short)f2bf(x.z); hv[3] = (short)f2bf(x.w);
        hv[4] = (short)f2bf(y.x); hv[5] = (short)f2bf(y.y);
        hv[6] = (short)f2bf(y.z); hv[7] = (short)f2bf(y.w);
        int c = seg * 4 + i;
        int cp = c ^ (row & 7);
        *(short8*)&fbs[row * 128 + cp * 8] = hv;
    }
}

// ---------------- weight prep + counts zero (fused) ----------------
__device__ __forceinline__ void tr_seg(const float* __restrict__ src, unsigned short* __restrict__ dst,
                                       int K, int Ncols, int idx) {
    int c = idx / K, k = idx - c * K;
    dst[idx] = f2bf(src[k * Ncols + c]);
}

__global__ void k_prep_w(const float* __restrict__ e_emb, const float* __restrict__ W1e,
                         const float* __restrict__ b1e, const float* __restrict__ W2e,
                         const float* __restrict__ W1s, const float* __restrict__ W2s,
                         unsigned short* __restrict__ Tb, unsigned short* __restrict__ W1ebT,
                         unsigned short* __restrict__ W2eT, unsigned short* __restrict__ W1sT,
                         unsigned short* __restrict__ W2sT, int* __restrict__ counts) {
    int tid = blockIdx.x * 256 + threadIdx.x;
    if (tid < PZ_CNT) {
        counts[tid] = 0;
    } else if (tid < PO_W1EB) {
        int idx = tid - PO_TB;
        int typ = idx >> 9, col = idx & 511;
        float acc = b1e[col];
        for (int k = 0; k < 128; ++k)
            acc += e_emb[typ * 128 + k] * W1e[k * 512 + col];
        Tb[idx] = f2bf(acc);
    } else if (tid < PO_W2E) {
        tr_seg(W1e + 128 * 512, W1ebT, 128, 512, tid - PO_W1EB);
    } else if (tid < PO_W1S) {
        tr_seg(W2e, W2eT, 512, 128, tid - PO_W2E);
    } else if (tid < PO_W2S) {
        tr_seg(W1s, W1sT, 128, 256, tid - PO_W1S);
    } else if (tid < P_TOTAL) {
        tr_seg(W2s, W2sT, 256, 128, tid - PO_W2S);
    }
}

// ---------------- counting sort of edges by dst (parallel 3-kernel scan, R6-proven) ----------------

__global__ void k_hist(const int* __restrict__ edge_dst, int* __restrict__ counts) {
    int e = blockIdx.x * 256 + threadIdx.x;
    if (e < N_EDGES) atomicAdd(&counts[edge_dst[e]], 1);
}

__global__ void k_scan1(const int* __restrict__ counts, int* __restrict__ blocksum) {
    __shared__ int s[256];
    int t = threadIdx.x;
    s[t] = counts[blockIdx.x * 256 + t];
    __syncthreads();
    for (int d = 128; d > 0; d >>= 1) {
        if (t < d) s[t] += s[t + d];
        __syncthreads();
    }
    if (t == 0) blocksum[blockIdx.x] = s[0];
}

__global__ void k_scan2(const int* __restrict__ blocksum, int* __restrict__ blockoff) {
    __shared__ int s[256];
    int t = threadIdx.x;
    int v = (t < NBLK) ? blocksum[t] : 0;
    s[t] = v;
    __syncthreads();
    for (int d = 1; d < 256; d <<= 1) {
        int x = (t >= d) ? s[t - d] : 0;
        __syncthreads();
        s[t] += x;
        __syncthreads();
    }
    if (t < NBLK) blockoff[t] = s[t] - v;
}

__global__ void k_scan3(const int* __restrict__ counts, const int* __restrict__ blockoff,
                        int* __restrict__ row_start, int* __restrict__ cursor) {
    __shared__ int s[256];
    int t = threadIdx.x;
    int i = blockIdx.x * 256 + t;
    int v = counts[i];
    s[t] = v;
    __syncthreads();
    for (int d = 1; d < 256; d <<= 1) {
        int x = (t >= d) ? s[t - d] : 0;
        __syncthreads();
        s[t] += x;
        __syncthreads();
    }
    int excl = s[t] - v + blockoff[blockIdx.x];
    row_start[i] = excl;
    cursor[i] = excl;
}

// pack src|type<<16 (src < 65536)
__global__ void k_scatter(const int* __restrict__ edge_src, const int* __restrict__ edge_dst,
                          const int* __restrict__ edge_type, int* __restrict__ cursor,
                          int* __restrict__ sorted_pack) {
    int e = blockIdx.x * 256 + threadIdx.x;
    if (e < N_EDGES) {
        int d = edge_dst[e];
        int pos = atomicAdd(&cursor[d], 1);
        sorted_pack[pos] = edge_src[e] | (edge_type[e] << 16);
    }
}

// ---------------- merged node kernel: G GEMM role / self MLP role ----------------

__device__ __forceinline__ void gemm_G_role(const float* __restrict__ features,
                                            const unsigned short* __restrict__ W1ebT,
                                            unsigned short* __restrict__ G,
                                            unsigned short* fbs, int bid) {
    int t = threadIdx.x, lane = t & 63, wave = t >> 6;
    int r = lane & 15, quad = lane >> 4;

    short8 bfrag[8][4];
    #pragma unroll
    for (int ct = 0; ct < 8; ++ct)
        #pragma unroll
        for (int ks = 0; ks < 4; ++ks)
            bfrag[ct][ks] = *(const short8*)&W1ebT[(wave * 128 + ct * 16 + r) * 128 + ks * 32 + quad * 8];

    for (int tile = bid; tile < N_TILES; tile += GRID_G) {
        int mbase = tile * 64;
        stage_feat(features, fbs, mbase, t);
        __syncthreads();
        #pragma unroll
        for (int m = 0; m < 4; ++m) {
            floatx4 acc[8];
            #pragma unroll
            for (int i = 0; i < 8; ++i) acc[i] = (floatx4){0.f, 0.f, 0.f, 0.f};
            #pragma unroll
            for (int ks = 0; ks < 4; ++ks) {
                int row = m * 16 + r;
                int cp = (ks * 4 + quad) ^ (row & 7);
                short8 a = *(const short8*)&fbs[row * 128 + cp * 8];
                #pragma unroll
                for (int ct = 0; ct < 8; ++ct)
                    acc[ct] = __builtin_amdgcn_mfma_f32_16x16x32_bf16(a, bfrag[ct][ks], acc[ct], 0, 0, 0);
            }
            #pragma unroll
            for (int ct = 0; ct < 8; ++ct)
                #pragma unroll
                for (int p = 0; p < 4; ++p) {
                    int node = mbase + m * 16 + quad * 4 + p;
                    if (node < N_NODES)
                        G[(size_t)node * 512 + wave * 128 + ct * 16 + r] = f2bf(acc[ct][p]);
                }
        }
        __syncthreads();
    }
}

__device__ __forceinline__ void self_role(const float* __restrict__ features,
                                          const unsigned short* __restrict__ W1sT,
                                          const float* __restrict__ b1s,
                                          const unsigned short* __restrict__ W2sT,
                                          const float* __restrict__ b2s,
                                          float* __restrict__ out,
                                          unsigned short* fbs, unsigned short* hss, int bid) {
    int t = threadIdx.x, lane = t & 63, wave = t >> 6;
    int r = lane & 15, quad = lane >> 4;

    short8 b1f[4][4];
    #pragma unroll
    for (int ct = 0; ct < 4; ++ct)
        #pragma unroll
        for (int ks = 0; ks < 4; ++ks)
            b1f[ct][ks] = *(const short8*)&W1sT[(wave * 64 + ct * 16 + r) * 128 + ks * 32 + quad * 8];
    short8 b2f[2][8];
    #pragma unroll
    for (int ct = 0; ct < 2; ++ct)
        #pragma unroll
        for (int ks = 0; ks < 8; ++ks)
            b2f[ct][ks] = *(const short8*)&W2sT[(wave * 32 + ct * 16 + r) * 256 + ks * 32 + quad * 8];
    float bias1[4], bias2[2];
    #pragma unroll
    for (int ct = 0; ct < 4; ++ct) bias1[ct] = b1s[wave * 64 + ct * 16 + r];
    #pragma unroll
    for (int ct = 0; ct < 2; ++ct) bias2[ct] = b2s[wave * 32 + ct * 16 + r];

    for (int tile = bid; tile < N_TILES; tile += GRID_G) {
        int mbase = tile * 64;
        stage_feat(features, fbs, mbase, t);
        __syncthreads();

        #pragma unroll
        for (int m = 0; m < 4; ++m) {
            floatx4 acc[4];
            #pragma unroll
            for (int i = 0; i < 4; ++i) acc[i] = (floatx4){0.f, 0.f, 0.f, 0.f};
            #pragma unroll
            for (int ks = 0; ks < 4; ++ks) {
                int row = m * 16 + r;
                int cp = (ks * 4 + quad) ^ (row & 7);
                short8 a = *(const short8*)&fbs[row * 128 + cp * 8];
                #pragma unroll
                for (int ct = 0; ct < 4; ++ct)
                    acc[ct] = __builtin_amdgcn_mfma_f32_16x16x32_bf16(a, b1f[ct][ks], acc[ct], 0, 0, 0);
            }
            #pragma unroll
            for (int ct = 0; ct < 4; ++ct)
                #pragma unroll
                for (int p = 0; p < 4; ++p) {
                    int lrow = m * 16 + quad * 4 + p;
                    int col = wave * 64 + ct * 16 + r;
                    float v = fmaxf(acc[ct][p] + bias1[ct], 0.f);
                    int cp = (col >> 3) ^ (lrow & 7);
                    hss[lrow * 256 + cp * 8 + (col & 7)] = f2bf(v);
                }
        }
        __syncthreads();

        #pragma unroll
        for (int m = 0; m < 4; ++m) {
            floatx4 acc[2];
            #pragma unroll
            for (int i = 0; i < 2; ++i) acc[i] = (floatx4){0.f, 0.f, 0.f, 0.f};
            #pragma unroll
            for (int ks = 0; ks < 8; ++ks) {
                int row = m * 16 + r;
                int cp = (ks * 4 + quad) ^ (row & 7);
                short8 a = *(const short8*)&hss[row * 256 + cp * 8];
                #pragma unroll
                for (int ct = 0; ct < 2; ++ct)
                    acc[ct] = __builtin_amdgcn_mfma_f32_16x16x32_bf16(a, b2f[ct][ks], acc[ct], 0, 0, 0);
            }
            #pragma unroll
            for (int ct = 0; ct < 2; ++ct)
                #pragma unroll
                for (int p = 0; p < 4; ++p) {
                    int node = mbase + m * 16 + quad * 4 + p;
                    if (node < N_NODES)
                        out[(size_t)node * 256 + wave * 32 + ct * 16 + r] = acc[ct][p] + bias2[ct];
                }
        }
        __syncthreads();
    }
}

__global__ __launch_bounds__(256, 2) void k_node(const float* __restrict__ features,
                                                 const unsigned short* __restrict__ W1ebT,
                                                 unsigned short* __restrict__ G,
                                                 const unsigned short* __restrict__ W1sT,
                                                 const float* __restrict__ b1s,
                                                 const unsigned short* __restrict__ W2sT,
                                                 const float* __restrict__ b2s,
                                                 float* __restrict__ out) {
    __shared__ unsigned short fbs[64 * 128];   // 16 KB
    __shared__ unsigned short hss[64 * 256];   // 32 KB (self role only)
    int bid = blockIdx.x;
    if (bid < GRID_G)
        gemm_G_role(features, W1ebT, G, fbs, bid);
    else
        self_role(features, W1sT, b1s, W2sT, b2s, out, fbs, hss, bid - GRID_G);
}

// ---------------- aggregation: H[n] = sum_e relu(G[src]+T[type])   [N,512] bf16 ----------------
// R8-proven 62 µs shape: wave-per-node, 12500 short blocks, no LDS, 4-edge unroll, bf16 Tb.
__global__ __launch_bounds__(256) void k_agg(const unsigned short* __restrict__ G,
                                             const unsigned short* __restrict__ Tb,
                                             const int* __restrict__ row_start,
                                             const int* __restrict__ sorted_pack,
                                             unsigned short* __restrict__ H) {
    int t = threadIdx.x, lane = t & 63, wave = t >> 6;
    int node = blockIdx.x * 4 + wave;
    if (node >= N_NODES) return;
    int beg = row_start[node], end = row_start[node + 1];
    float acc[8] = {0.f, 0.f, 0.f, 0.f, 0.f, 0.f, 0.f, 0.f};
    int off = lane * 8;
    int e = beg;
    for (; e + 4 <= end; e += 4) {
        int v0 = sorted_pack[e],     v1 = sorted_pack[e + 1];
        int v2 = sorted_pack[e + 2], v3 = sorted_pack[e + 3];
        short8 g0 = *(const short8*)&G[(unsigned)(v0 & 0xFFFF) * 512 + off];
        short8 g1 = *(const short8*)&G[(unsigned)(v1 & 0xFFFF) * 512 + off];
        short8 g2 = *(const short8*)&G[(unsigned)(v2 & 0xFFFF) * 512 + off];
        short8 g3 = *(const short8*)&G[(unsigned)(v3 & 0xFFFF) * 512 + off];
        short8 u0 = *(const short8*)&Tb[(v0 >> 16) * 512 + off];
        short8 u1 = *(const short8*)&Tb[(v1 >> 16) * 512 + off];
        short8 u2 = *(const short8*)&Tb[(v2 >> 16) * 512 + off];
        short8 u3 = *(const short8*)&Tb[(v3 >> 16) * 512 + off];
        #pragma unroll
        for (int k = 0; k < 8; ++k) {
            acc[k] += fmaxf(bf2f((unsigned short)g0[k]) + bf2f((unsigned short)u0[k]), 0.f);
            acc[k] += fmaxf(bf2f((unsigned short)g1[k]) + bf2f((unsigned short)u1[k]), 0.f);
            acc[k] += fmaxf(bf2f((unsigned short)g2[k]) + bf2f((unsigned short)u2[k]), 0.f);
            acc[k] += fmaxf(bf2f((unsigned short)g3[k]) + bf2f((unsigned short)u3[k]), 0.f);
        }
    }
    for (; e < end; ++e) {
        int v = sorted_pack[e];
        short8 g0 = *(const short8*)&G[(unsigned)(v & 0xFFFF) * 512 + off];
        short8 u0 = *(const short8*)&Tb[(v >> 16) * 512 + off];
        #pragma unroll
        for (int k = 0; k < 8; ++k)
            acc[k] += fmaxf(bf2f((unsigned short)g0[k]) + bf2f((unsigned short)u0[k]), 0.f);
    }
    short8 hv;
    #pragma unroll
    for (int k = 0; k < 8; ++k) hv[k] = (short)f2bf(acc[k]);
    *(short8*)&H[(size_t)node * 512 + off] = hv;
}

// ---------------- out[:,128:] = H @ W2e + deg*b2e ----------------
__global__ __launch_bounds__(256, 2) void k_gemm_H(const unsigned short* __restrict__ H,
                                                   const int* __restrict__ row_start,
                                                   const unsigned short* __restrict__ W2eT,
                                                   const float* __restrict__ b2e,
                                                   float* __restrict__ out) {
    __shared__ unsigned short hls[64 * 512];   // 64 KB
    int t = threadIdx.x, lane = t & 63, wave = t >> 6;
    int r = lane & 15, quad = lane >> 4;

    short8 bf[2][16];
    #pragma unroll
    for (int ct = 0; ct < 2; ++ct)
        #pragma unroll
        for (int ks = 0; ks < 16; ++ks)
            bf[ct][ks] = *(const short8*)&W2eT[(wave * 32 + ct * 16 + r) * 512 + ks * 32 + quad * 8];
    float bias[2];
    #pragma unroll
    for (int ct = 0; ct < 2; ++ct) bias[ct] = b2e[wave * 32 + ct * 16 + r];

    for (int tile = blockIdx.x; tile < N_TILES; tile += GRID_G) {
        int nbase = tile * 64;
        {
            int row = t >> 2, seg = t & 3;
            int node = nbase + row; if (node >= N_NODES) node = N_NODES - 1;
            const unsigned short* p = &H[(size_t)node * 512 + seg * 128];
            #pragma unroll
            for (int i = 0; i < 16; ++i) {
                int c = seg * 16 + i;
                int cp = c ^ (row & 7);
                *(short8*)&hls[row * 512 + cp * 8] = *(const short8*)&p[i * 8];
            }
        }
        __syncthreads();
        #pragma unroll
        for (int m = 0; m < 4; ++m) {
            floatx4 acc[2];
            #pragma unroll
            for (int i = 0; i < 2; ++i) acc[i] = (floatx4){0.f, 0.f, 0.f, 0.f};
            #pragma unroll
            for (int ks = 0; ks < 16; ++ks) {
                int row = m * 16 + r;
                int cp = (ks * 4 + quad) ^ (row & 7);
                short8 a = *(const short8*)&hls[row * 512 + cp * 8];
                #pragma unroll
                for (int ct = 0; ct < 2; ++ct)
                    acc[ct] = __builtin_amdgcn_mfma_f32_16x16x32_bf16(a, bf[ct][ks], acc[ct], 0, 0, 0);
            }
            #pragma unroll
            for (int p = 0; p < 4; ++p) {
                int node = nbase + m * 16 + quad * 4 + p;
                if (node < N_NODES) {
                    float dg = (float)(row_start[node + 1] - row_start[node]);
                    #pragma unroll
                    for (int ct = 0; ct < 2; ++ct)
                        out[(size_t)node * 256 + 128 + wave * 32 + ct * 16 + r] = acc[ct][p] + dg * bias[ct];
                }
            }
        }
        __syncthreads();
    }
}

// ---------------- launch ----------------

extern "C" void kernel_launch(void* const* d_in, const int* in_sizes, int n_in,
                              void* d_out, int out_size, void* d_ws, size_t ws_size,
                              hipStream_t stream) {
    const float* features  = (const float*)d_in[0];
    const int*   edge_src  = (const int*)d_in[1];
    const int*   edge_dst  = (const int*)d_in[2];
    const int*   edge_type = (const int*)d_in[3];
    const float* e_emb     = (const float*)d_in[4];
    const float* W1e       = (const float*)d_in[5];
    const float* b1e       = (const float*)d_in[6];
    const float* W2e       = (const float*)d_in[7];
    const float* b2e       = (const float*)d_in[8];
    const float* W1s       = (const float*)d_in[9];
    const float* b1s       = (const float*)d_in[10];
    const float* W2s       = (const float*)d_in[11];
    const float* b2s       = (const float*)d_in[12];
    float* out = (float*)d_out;

    char* ws = (char*)d_ws;
    size_t off = 0;
    auto alloc = [&](size_t bytes) {
        char* p = ws + off;
        off += (bytes + 255) & ~(size_t)255;
        return p;
    };
    unsigned short* G        = (unsigned short*)alloc((size_t)N_NODES * 512 * 2);
    unsigned short* H        = (unsigned short*)alloc((size_t)N_NODES * 512 * 2);
    unsigned short* Tb       = (unsigned short*)alloc(16 * 512 * 2);
    unsigned short* W1ebT    = (unsigned short*)alloc(512 * 128 * 2);
    unsigned short* W2eT     = (unsigned short*)alloc(128 * 512 * 2);
    unsigned short* W1sT     = (unsigned short*)alloc(256 * 128 * 2);
    unsigned short* W2sT     = (unsigned short*)alloc(128 * 256 * 2);
    int* counts      = (int*)alloc((size_t)N_PAD * 4);
    int* row_start   = (int*)alloc((size_t)N_PAD * 4);
    int* cursor      = (int*)alloc((size_t)N_PAD * 4);
    int* blocksum    = (int*)alloc(256 * 4);
    int* blockoff    = (int*)alloc(256 * 4);
    int* sorted_pack = (int*)alloc((size_t)N_EDGES * 4);

    k_prep_w<<<P_TOTAL / 256, 256, 0, stream>>>(e_emb, W1e, b1e, W2e, W1s, W2s,
                                                Tb, W1ebT, W2eT, W1sT, W2sT, counts);

    k_hist<<<(N_EDGES + 255) / 256, 256, 0, stream>>>(edge_dst, counts);
    k_scan1<<<NBLK, 256, 0, stream>>>(counts, blocksum);
    k_scan2<<<1, 256, 0, stream>>>(blocksum, blockoff);
    k_scan3<<<NBLK, 256, 0, stream>>>(counts, blockoff, row_start, cursor);
    k_scatter<<<(N_EDGES + 255) / 256, 256, 0, stream>>>(edge_src, edge_dst, edge_type,
                                                         cursor, sorted_pack);

    k_node<<<GRID_G * 2, 256, 0, stream>>>(features, W1ebT, G, W1sT, b1s, W2sT, b2s, out);
    k_agg<<<(N_NODES + 3) / 4, 256, 0, stream>>>(G, Tb, row_start, sorted_pack, H);
    k_gemm_H<<<GRID_G, 256, 0, stream>>>(H, row_start, W2eT, b2e, out);
}

// Round 10
// 260.417 us; speedup vs baseline: 1.2253x; 1.0707x over previous
//
#include <hip/hip_runtime.h>

#define N_NODES 50000
#define N_EDGES 400000
#define N_TILES 782          // ceil(50000/64)
#define GRID_G  512

#define N_PAD   50176        // 196 * 256
#define NBLK    196

// k_prep_w segment offsets (thread ids)
#define PZ_CNT   50176                    // [0, PZ_CNT): zero counts
#define PO_TB    (PZ_CNT)                 // 8192: Tb (bf16)
#define PO_W1EB  (PO_TB + 8192)           // 65536: W1ebT
#define PO_W2E   (PO_W1EB + 65536)        // 65536: W2eT
#define PO_W1S   (PO_W2E + 65536)        // 32768: W1sT
#define PO_W2S   (PO_W1S + 32768)         // 32768: W2sT
#define P_TOTAL  (PO_W2S + 32768)         // 254976 = 996 * 256

typedef __attribute__((ext_vector_type(8))) short short8;
typedef __attribute__((ext_vector_type(4))) float floatx4;
typedef __attribute__((ext_vector_type(2))) float floatx2;

__device__ __forceinline__ float bf2f(unsigned short u) {
    union { unsigned int i; float f; } v; v.i = ((unsigned int)u) << 16; return v.f;
}
__device__ __forceinline__ unsigned short f2bf(float f) {
    union { float f; unsigned int i; } v; v.f = f;
    unsigned int b = v.i;
    return (unsigned short)((b + 0x7FFFu + ((b >> 16) & 1u)) >> 16);
}

// stage one 64-row x 128-col f32 tile -> swizzled bf16 LDS tile (16 KB)
__device__ __forceinline__ void stage_feat(const float* __restrict__ features,
                                           unsigned short* __restrict__ fbs,
                                           int mbase, int t) {
    int row = t >> 2, seg = t & 3;
    int node = mbase + row; if (node >= N_NODES) node = N_NODES - 1;
    const float* p = &features[(size_t)node * 128 + seg * 32];
    #pragma unroll
    for (int i = 0; i < 4; ++i) {
        float4 x = *(const float4*)&p[i * 8];
        float4 y = *(const float4*)&p[i * 8 + 4];
        short8 hv;
        hv[0] = (short)f2bf(x.x); hv[1] = (short)f2bf(x.y);
        hv[2] = (short)f2bf(x.z); hv[3] = (short)f2bf(x.w);
        hv[4] = (short)f2bf(y.x); hv[5] = (short)f2bf(y.y);
        hv[6] = (short)f2bf(y.z); hv[7] = (short)f2bf(y.w);
        int c = seg * 4 + i;
        int cp = c ^ (row & 7);
        *(short8*)&fbs[row * 128 + cp * 8] = hv;
    }
}

// ---------------- weight prep + counts zero (fused) ----------------
__device__ __forceinline__ void tr_seg(const float* __restrict__ src, unsigned short* __restrict__ dst,
                                       int K, int Ncols, int idx) {
    int c = idx / K, k = idx - c * K;
    dst[idx] = f2bf(src[k * Ncols + c]);
}

__global__ void k_prep_w(const float* __restrict__ e_emb, const float* __restrict__ W1e,
                         const float* __restrict__ b1e, const float* __restrict__ W2e,
                         const float* __restrict__ W1s, const float* __restrict__ W2s,
                         unsigned short* __restrict__ Tb, unsigned short* __restrict__ W1ebT,
                         unsigned short* __restrict__ W2eT, unsigned short* __restrict__ W1sT,
                         unsigned short* __restrict__ W2sT, int* __restrict__ counts) {
    int tid = blockIdx.x * 256 + threadIdx.x;
    if (tid < PZ_CNT) {
        counts[tid] = 0;
    } else if (tid < PO_W1EB) {
        int idx = tid - PO_TB;
        int typ = idx >> 9, col = idx & 511;
        float acc = b1e[col];
        for (int k = 0; k < 128; ++k)
            acc += e_emb[typ * 128 + k] * W1e[k * 512 + col];
        Tb[idx] = f2bf(acc);
    } else if (tid < PO_W2E) {
        tr_seg(W1e + 128 * 512, W1ebT, 128, 512, tid - PO_W1EB);
    } else if (tid < PO_W1S) {
        tr_seg(W2e, W2eT, 512, 128, tid - PO_W2E);
    } else if (tid < PO_W2S) {
        tr_seg(W1s, W1sT, 128, 256, tid - PO_W1S);
    } else if (tid < P_TOTAL) {
        tr_seg(W2s, W2sT, 256, 128, tid - PO_W2S);
    }
}

// ---------------- counting sort of edges by dst (parallel 3-kernel scan) ----------------

__global__ void k_hist(const int* __restrict__ edge_dst, int* __restrict__ counts) {
    int e = blockIdx.x * 256 + threadIdx.x;
    if (e < N_EDGES) atomicAdd(&counts[edge_dst[e]], 1);
}

__global__ void k_scan1(const int* __restrict__ counts, int* __restrict__ blocksum) {
    __shared__ int s[256];
    int t = threadIdx.x;
    s[t] = counts[blockIdx.x * 256 + t];
    __syncthreads();
    for (int d = 128; d > 0; d >>= 1) {
        if (t < d) s[t] += s[t + d];
        __syncthreads();
    }
    if (t == 0) blocksum[blockIdx.x] = s[0];
}

__global__ void k_scan2(const int* __restrict__ blocksum, int* __restrict__ blockoff) {
    __shared__ int s[256];
    int t = threadIdx.x;
    int v = (t < NBLK) ? blocksum[t] : 0;
    s[t] = v;
    __syncthreads();
    for (int d = 1; d < 256; d <<= 1) {
        int x = (t >= d) ? s[t - d] : 0;
        __syncthreads();
        s[t] += x;
        __syncthreads();
    }
    if (t < NBLK) blockoff[t] = s[t] - v;
}

__global__ void k_scan3(const int* __restrict__ counts, const int* __restrict__ blockoff,
                        int* __restrict__ row_start, int* __restrict__ cursor) {
    __shared__ int s[256];
    int t = threadIdx.x;
    int i = blockIdx.x * 256 + t;
    int v = counts[i];
    s[t] = v;
    __syncthreads();
    for (int d = 1; d < 256; d <<= 1) {
        int x = (t >= d) ? s[t - d] : 0;
        __syncthreads();
        s[t] += x;
        __syncthreads();
    }
    int excl = s[t] - v + blockoff[blockIdx.x];
    row_start[i] = excl;
    cursor[i] = excl;
}

// pack src|type<<16 (src < 65536)
__global__ void k_scatter(const int* __restrict__ edge_src, const int* __restrict__ edge_dst,
                          const int* __restrict__ edge_type, int* __restrict__ cursor,
                          int* __restrict__ sorted_pack) {
    int e = blockIdx.x * 256 + threadIdx.x;
    if (e < N_EDGES) {
        int d = edge_dst[e];
        int pos = atomicAdd(&cursor[d], 1);
        sorted_pack[pos] = edge_src[e] | (edge_type[e] << 16);
    }
}

// ---------------- merged node kernel: G GEMM role / self MLP role ----------------

__device__ __forceinline__ void gemm_G_role(const float* __restrict__ features,
                                            const unsigned short* __restrict__ W1ebT,
                                            unsigned char* __restrict__ G8,
                                            unsigned short* fbs, int bid) {
    int t = threadIdx.x, lane = t & 63, wave = t >> 6;
    int r = lane & 15, quad = lane >> 4;

    short8 bfrag[8][4];
    #pragma unroll
    for (int ct = 0; ct < 8; ++ct)
        #pragma unroll
        for (int ks = 0; ks < 4; ++ks)
            bfrag[ct][ks] = *(const short8*)&W1ebT[(wave * 128 + ct * 16 + r) * 128 + ks * 32 + quad * 8];

    for (int tile = bid; tile < N_TILES; tile += GRID_G) {
        int mbase = tile * 64;
        stage_feat(features, fbs, mbase, t);
        __syncthreads();
        #pragma unroll
        for (int m = 0; m < 4; ++m) {
            floatx4 acc[8];
            #pragma unroll
            for (int i = 0; i < 8; ++i) acc[i] = (floatx4){0.f, 0.f, 0.f, 0.f};
            #pragma unroll
            for (int ks = 0; ks < 4; ++ks) {
                int row = m * 16 + r;
                int cp = (ks * 4 + quad) ^ (row & 7);
                short8 a = *(const short8*)&fbs[row * 128 + cp * 8];
                #pragma unroll
                for (int ct = 0; ct < 8; ++ct)
                    acc[ct] = __builtin_amdgcn_mfma_f32_16x16x32_bf16(a, bfrag[ct][ks], acc[ct], 0, 0, 0);
            }
            #pragma unroll
            for (int ct = 0; ct < 8; ++ct)
                #pragma unroll
                for (int p = 0; p < 4; ++p) {
                    int node = mbase + m * 16 + quad * 4 + p;
                    if (node < N_NODES) {
                        int w = __builtin_amdgcn_cvt_pk_fp8_f32(acc[ct][p], acc[ct][p], 0, false);
                        G8[(size_t)node * 512 + wave * 128 + ct * 16 + r] = (unsigned char)w;
                    }
                }
        }
        __syncthreads();
    }
}

__device__ __forceinline__ void self_role(const float* __restrict__ features,
                                          const unsigned short* __restrict__ W1sT,
                                          const float* __restrict__ b1s,
                                          const unsigned short* __restrict__ W2sT,
                                          const float* __restrict__ b2s,
                                          float* __restrict__ out,
                                          unsigned short* fbs, unsigned short* hss, int bid) {
    int t = threadIdx.x, lane = t & 63, wave = t >> 6;
    int r = lane & 15, quad = lane >> 4;

    short8 b1f[4][4];
    #pragma unroll
    for (int ct = 0; ct < 4; ++ct)
        #pragma unroll
        for (int ks = 0; ks < 4; ++ks)
            b1f[ct][ks] = *(const short8*)&W1sT[(wave * 64 + ct * 16 + r) * 128 + ks * 32 + quad * 8];
    short8 b2f[2][8];
    #pragma unroll
    for (int ct = 0; ct < 2; ++ct)
        #pragma unroll
        for (int ks = 0; ks < 8; ++ks)
            b2f[ct][ks] = *(const short8*)&W2sT[(wave * 32 + ct * 16 + r) * 256 + ks * 32 + quad * 8];
    float bias1[4], bias2[2];
    #pragma unroll
    for (int ct = 0; ct < 4; ++ct) bias1[ct] = b1s[wave * 64 + ct * 16 + r];
    #pragma unroll
    for (int ct = 0; ct < 2; ++ct) bias2[ct] = b2s[wave * 32 + ct * 16 + r];

    for (int tile = bid; tile < N_TILES; tile += GRID_G) {
        int mbase = tile * 64;
        stage_feat(features, fbs, mbase, t);
        __syncthreads();

        #pragma unroll
        for (int m = 0; m < 4; ++m) {
            floatx4 acc[4];
            #pragma unroll
            for (int i = 0; i < 4; ++i) acc[i] = (floatx4){0.f, 0.f, 0.f, 0.f};
            #pragma unroll
            for (int ks = 0; ks < 4; ++ks) {
                int row = m * 16 + r;
                int cp = (ks * 4 + quad) ^ (row & 7);
                short8 a = *(const short8*)&fbs[row * 128 + cp * 8];
                #pragma unroll
                for (int ct = 0; ct < 4; ++ct)
                    acc[ct] = __builtin_amdgcn_mfma_f32_16x16x32_bf16(a, b1f[ct][ks], acc[ct], 0, 0, 0);
            }
            #pragma unroll
            for (int ct = 0; ct < 4; ++ct)
                #pragma unroll
                for (int p = 0; p < 4; ++p) {
                    int lrow = m * 16 + quad * 4 + p;
                    int col = wave * 64 + ct * 16 + r;
                    float v = fmaxf(acc[ct][p] + bias1[ct], 0.f);
                    int cp = (col >> 3) ^ (lrow & 7);
                    hss[lrow * 256 + cp * 8 + (col & 7)] = f2bf(v);
                }
        }
        __syncthreads();

        #pragma unroll
        for (int m = 0; m < 4; ++m) {
            floatx4 acc[2];
            #pragma unroll
            for (int i = 0; i < 2; ++i) acc[i] = (floatx4){0.f, 0.f, 0.f, 0.f};
            #pragma unroll
            for (int ks = 0; ks < 8; ++ks) {
                int row = m * 16 + r;
                int cp = (ks * 4 + quad) ^ (row & 7);
                short8 a = *(const short8*)&hss[row * 256 + cp * 8];
                #pragma unroll
                for (int ct = 0; ct < 2; ++ct)
                    acc[ct] = __builtin_amdgcn_mfma_f32_16x16x32_bf16(a, b2f[ct][ks], acc[ct], 0, 0, 0);
            }
            #pragma unroll
            for (int ct = 0; ct < 2; ++ct)
                #pragma unroll
                for (int p = 0; p < 4; ++p) {
                    int node = mbase + m * 16 + quad * 4 + p;
                    if (node < N_NODES)
                        out[(size_t)node * 256 + wave * 32 + ct * 16 + r] = acc[ct][p] + bias2[ct];
                }
        }
        __syncthreads();
    }
}

__global__ __launch_bounds__(256, 2) void k_node(const float* __restrict__ features,
                                                 const unsigned short* __restrict__ W1ebT,
                                                 unsigned char* __restrict__ G8,
                                                 const unsigned short* __restrict__ W1sT,
                                                 const float* __restrict__ b1s,
                                                 const unsigned short* __restrict__ W2sT,
                                                 const float* __restrict__ b2s,
                                                 float* __restrict__ out) {
    __shared__ unsigned short fbs[64 * 128];   // 16 KB
    __shared__ unsigned short hss[64 * 256];   // 32 KB (self role only)
    int bid = blockIdx.x;
    if (bid < GRID_G)
        gemm_G_role(features, W1ebT, G8, fbs, bid);
    else
        self_role(features, W1sT, b1s, W2sT, b2s, out, fbs, hss, bid - GRID_G);
}

// ---------------- aggregation: H[n] = sum_e relu(G[src]+T[type])   [N,512] bf16 ----------------
// wave-per-node, 12500 short blocks, no LDS, 4-edge unroll; G in fp8 (8 B/lane/edge).
__device__ __forceinline__ void acc_edge(float* acc, int2 g, short8 u) {
    floatx2 f0 = __builtin_amdgcn_cvt_pk_f32_fp8(g.x, false);
    floatx2 f1 = __builtin_amdgcn_cvt_pk_f32_fp8(g.x, true);
    floatx2 f2 = __builtin_amdgcn_cvt_pk_f32_fp8(g.y, false);
    floatx2 f3 = __builtin_amdgcn_cvt_pk_f32_fp8(g.y, true);
    acc[0] += fmaxf(f0.x + bf2f((unsigned short)u[0]), 0.f);
    acc[1] += fmaxf(f0.y + bf2f((unsigned short)u[1]), 0.f);
    acc[2] += fmaxf(f1.x + bf2f((unsigned short)u[2]), 0.f);
    acc[3] += fmaxf(f1.y + bf2f((unsigned short)u[3]), 0.f);
    acc[4] += fmaxf(f2.x + bf2f((unsigned short)u[4]), 0.f);
    acc[5] += fmaxf(f2.y + bf2f((unsigned short)u[5]), 0.f);
    acc[6] += fmaxf(f3.x + bf2f((unsigned short)u[6]), 0.f);
    acc[7] += fmaxf(f3.y + bf2f((unsigned short)u[7]), 0.f);
}

__global__ __launch_bounds__(256) void k_agg(const unsigned char* __restrict__ G8,
                                             const unsigned short* __restrict__ Tb,
                                             const int* __restrict__ row_start,
                                             const int* __restrict__ sorted_pack,
                                             unsigned short* __restrict__ H) {
    int t = threadIdx.x, lane = t & 63, wave = t >> 6;
    int node = blockIdx.x * 4 + wave;
    if (node >= N_NODES) return;
    int beg = row_start[node], end = row_start[node + 1];
    float acc[8] = {0.f, 0.f, 0.f, 0.f, 0.f, 0.f, 0.f, 0.f};
    int goff = lane * 8;      // byte offset into 512-B fp8 row
    int toff = lane * 8;      // element offset into 512-elem bf16 row
    int e = beg;
    for (; e + 4 <= end; e += 4) {
        int v0 = sorted_pack[e],     v1 = sorted_pack[e + 1];
        int v2 = sorted_pack[e + 2], v3 = sorted_pack[e + 3];
        int2 g0 = *(const int2*)&G8[(unsigned)(v0 & 0xFFFF) * 512 + goff];
        int2 g1 = *(const int2*)&G8[(unsigned)(v1 & 0xFFFF) * 512 + goff];
        int2 g2 = *(const int2*)&G8[(unsigned)(v2 & 0xFFFF) * 512 + goff];
        int2 g3 = *(const int2*)&G8[(unsigned)(v3 & 0xFFFF) * 512 + goff];
        short8 u0 = *(const short8*)&Tb[(v0 >> 16) * 512 + toff];
        short8 u1 = *(const short8*)&Tb[(v1 >> 16) * 512 + toff];
        short8 u2 = *(const short8*)&Tb[(v2 >> 16) * 512 + toff];
        short8 u3 = *(const short8*)&Tb[(v3 >> 16) * 512 + toff];
        acc_edge(acc, g0, u0);
        acc_edge(acc, g1, u1);
        acc_edge(acc, g2, u2);
        acc_edge(acc, g3, u3);
    }
    for (; e < end; ++e) {
        int v = sorted_pack[e];
        int2 g0 = *(const int2*)&G8[(unsigned)(v & 0xFFFF) * 512 + goff];
        short8 u0 = *(const short8*)&Tb[(v >> 16) * 512 + toff];
        acc_edge(acc, g0, u0);
    }
    short8 hv;
    #pragma unroll
    for (int k = 0; k < 8; ++k) hv[k] = (short)f2bf(acc[k]);
    *(short8*)&H[(size_t)node * 512 + toff] = hv;
}

// ---------------- out[:,128:] = H @ W2e + deg*b2e ----------------
__global__ __launch_bounds__(256, 2) void k_gemm_H(const unsigned short* __restrict__ H,
                                                   const int* __restrict__ row_start,
                                                   const unsigned short* __restrict__ W2eT,
                                                   const float* __restrict__ b2e,
                                                   float* __restrict__ out) {
    __shared__ unsigned short hls[64 * 512];   // 64 KB
    int t = threadIdx.x, lane = t & 63, wave = t >> 6;
    int r = lane & 15, quad = lane >> 4;

    short8 bf[2][16];
    #pragma unroll
    for (int ct = 0; ct < 2; ++ct)
        #pragma unroll
        for (int ks = 0; ks < 16; ++ks)
            bf[ct][ks] = *(const short8*)&W2eT[(wave * 32 + ct * 16 + r) * 512 + ks * 32 + quad * 8];
    float bias[2];
    #pragma unroll
    for (int ct = 0; ct < 2; ++ct) bias[ct] = b2e[wave * 32 + ct * 16 + r];

    for (int tile = blockIdx.x; tile < N_TILES; tile += GRID_G) {
        int nbase = tile * 64;
        {
            int row = t >> 2, seg = t & 3;
            int node = nbase + row; if (node >= N_NODES) node = N_NODES - 1;
            const unsigned short* p = &H[(size_t)node * 512 + seg * 128];
            #pragma unroll
            for (int i = 0; i < 16; ++i) {
                int c = seg * 16 + i;
                int cp = c ^ (row & 7);
                *(short8*)&hls[row * 512 + cp * 8] = *(const short8*)&p[i * 8];
            }
        }
        __syncthreads();
        #pragma unroll
        for (int m = 0; m < 4; ++m) {
            floatx4 acc[2];
            #pragma unroll
            for (int i = 0; i < 2; ++i) acc[i] = (floatx4){0.f, 0.f, 0.f, 0.f};
            #pragma unroll
            for (int ks = 0; ks < 16; ++ks) {
                int row = m * 16 + r;
                int cp = (ks * 4 + quad) ^ (row & 7);
                short8 a = *(const short8*)&hls[row * 512 + cp * 8];
                #pragma unroll
                for (int ct = 0; ct < 2; ++ct)
                    acc[ct] = __builtin_amdgcn_mfma_f32_16x16x32_bf16(a, bf[ct][ks], acc[ct], 0, 0, 0);
            }
            #pragma unroll
            for (int p = 0; p < 4; ++p) {
                int node = nbase + m * 16 + quad * 4 + p;
                if (node < N_NODES) {
                    float dg = (float)(row_start[node + 1] - row_start[node]);
                    #pragma unroll
                    for (int ct = 0; ct < 2; ++ct)
                        out[(size_t)node * 256 + 128 + wave * 32 + ct * 16 + r] = acc[ct][p] + dg * bias[ct];
                }
            }
        }
        __syncthreads();
    }
}

// ---------------- launch ----------------

extern "C" void kernel_launch(void* const* d_in, const int* in_sizes, int n_in,
                              void* d_out, int out_size, void* d_ws, size_t ws_size,
                              hipStream_t stream) {
    const float* features  = (const float*)d_in[0];
    const int*   edge_src  = (const int*)d_in[1];
    const int*   edge_dst  = (const int*)d_in[2];
    const int*   edge_type = (const int*)d_in[3];
    const float* e_emb     = (const float*)d_in[4];
    const float* W1e       = (const float*)d_in[5];
    const float* b1e       = (const float*)d_in[6];
    const float* W2e       = (const float*)d_in[7];
    const float* b2e       = (const float*)d_in[8];
    const float* W1s       = (const float*)d_in[9];
    const float* b1s       = (const float*)d_in[10];
    const float* W2s       = (const float*)d_in[11];
    const float* b2s       = (const float*)d_in[12];
    float* out = (float*)d_out;

    char* ws = (char*)d_ws;
    size_t off = 0;
    auto alloc = [&](size_t bytes) {
        char* p = ws + off;
        off += (bytes + 255) & ~(size_t)255;
        return p;
    };
    unsigned char*  G8       = (unsigned char*)alloc((size_t)N_NODES * 512);
    unsigned short* H        = (unsigned short*)alloc((size_t)N_NODES * 512 * 2);
    unsigned short* Tb       = (unsigned short*)alloc(16 * 512 * 2);
    unsigned short* W1ebT    = (unsigned short*)alloc(512 * 128 * 2);
    unsigned short* W2eT     = (unsigned short*)alloc(128 * 512 * 2);
    unsigned short* W1sT     = (unsigned short*)alloc(256 * 128 * 2);
    unsigned short* W2sT     = (unsigned short*)alloc(128 * 256 * 2);
    int* counts      = (int*)alloc((size_t)N_PAD * 4);
    int* row_start   = (int*)alloc((size_t)N_PAD * 4);
    int* cursor      = (int*)alloc((size_t)N_PAD * 4);
    int* blocksum    = (int*)alloc(256 * 4);
    int* blockoff    = (int*)alloc(256 * 4);
    int* sorted_pack = (int*)alloc((size_t)N_EDGES * 4);

    k_prep_w<<<P_TOTAL / 256, 256, 0, stream>>>(e_emb, W1e, b1e, W2e, W1s, W2s,
                                                Tb, W1ebT, W2eT, W1sT, W2sT, counts);

    k_hist<<<(N_EDGES + 255) / 256, 256, 0, stream>>>(edge_dst, counts);
    k_scan1<<<NBLK, 256, 0, stream>>>(counts, blocksum);
    k_scan2<<<1, 256, 0, stream>>>(blocksum, blockoff);
    k_scan3<<<NBLK, 256, 0, stream>>>(counts, blockoff, row_start, cursor);
    k_scatter<<<(N_EDGES + 255) / 256, 256, 0, stream>>>(edge_src, edge_dst, edge_type,
                                                         cursor, sorted_pack);

    k_node<<<GRID_G * 2, 256, 0, stream>>>(features, W1ebT, G8, W1sT, b1s, W2sT, b2s, out);
    k_agg<<<(N_NODES + 3) / 4, 256, 0, stream>>>(G8, Tb, row_start, sorted_pack, H);
    k_gemm_H<<<GRID_G, 256, 0, stream>>>(H, row_start, W2eT, b2e, out);
}